// Round 6
// baseline (175.892 us; speedup 1.0000x reference)
//
#include <hip/hip_runtime.h>
#include <hip/hip_bf16.h>
#include <math.h>

// NonLocalBlock: B=4, C=64, H=W=64 -> N=4096, CI=32. f32 I/O, bf16 MFMA.
// Softmax: logits s[q][k] = x_q·x_k shifted by diag K[q]=|x_q|^2 (Cauchy-Schwarz
// bounds shifted logits <= ~35, diag-shift = 0 => no overflow, denom >= ~1):
// softmax = pure exp + linear accumulation; key-split partials add.
// Round 6: Q pre-scaled by log2(e) so p = exp2(S) with S = log2e*(x_q·x_k - K[q]);
// the shift rides in the MFMA accumulator init; P packed to bf16 via v_perm.
#define B_  4
#define C_  64
#define N_  4096
#define CI_ 32
#define L2E 1.4426950408889634f

typedef __attribute__((ext_vector_type(8))) unsigned short u16x8;
typedef __attribute__((ext_vector_type(8))) __bf16        bf16x8;
typedef __attribute__((ext_vector_type(4))) float         f32x4;

__device__ __forceinline__ unsigned short f2bf(float f) {
    union { float f; unsigned int i; } v; v.f = f;
    unsigned int r = v.i + 0x7FFFu + ((v.i >> 16) & 1u);
    return (unsigned short)(r >> 16);
}

// ---------------------------------------------------------------------------
// Kernel 1 (fused prep): per 64-n tile of one batch:
//   xT[b][n][c] (bf16)  <- x transposed            (K operand)
//   xq[b][n][c] (bf16)  <- x transposed * log2e    (Q operand)
//   gx[b][o][n] (bf16)  <- Wg x + bg               (V operand)
//   diagS[b][n] (f32)   <- |x_n|^2 * log2e         (softmax shift, base-2)
// Grid 256 = b(4) x ntile(64). Block 256.
// ---------------------------------------------------------------------------
__global__ __launch_bounds__(256) void k_prep(
    const float* __restrict__ x, const float* __restrict__ Wg,
    const float* __restrict__ bg, unsigned short* __restrict__ xT,
    unsigned short* __restrict__ xq, unsigned short* __restrict__ gx,
    float* __restrict__ diagS)
{
    __shared__ __align__(16) float tile[64][68];
    __shared__ float part[4][64][33];   // o 0..31 = gx, col 32 = diag
    const int t  = threadIdx.x;
    const int b  = blockIdx.x >> 6;
    const int n0 = (blockIdx.x & 63) * 64;

    #pragma unroll
    for (int pass = 0; pass < 4; ++pass) {
        int c   = (t >> 4) + pass * 16;
        int nl4 = (t & 15) * 4;
        float4 v = *(const float4*)(x + (size_t)(b * C_ + c) * N_ + n0 + nl4);
        *(float4*)&tile[c][nl4] = v;
    }
    __syncthreads();

    // (a) xT and xq (bf16 transpose, xq scaled by log2e)
    {
        const int n  = t >> 2;
        const int cc = (t & 3) * 16;
        u16x8 a, b2, as, bs;
        #pragma unroll
        for (int j = 0; j < 8; ++j) {
            float v0 = tile[cc + j][n], v1 = tile[cc + 8 + j][n];
            a[j]  = f2bf(v0);        b2[j] = f2bf(v1);
            as[j] = f2bf(v0 * L2E);  bs[j] = f2bf(v1 * L2E);
        }
        size_t off = (size_t)(b * N_ + n0 + n) * C_ + cc;
        *(u16x8*)(xT + off)     = a;  *(u16x8*)(xT + off + 8) = b2;
        *(u16x8*)(xq + off)     = as; *(u16x8*)(xq + off + 8) = bs;
    }
    // (b) gx partial + diag partial
    {
        const int nl = t & 63, cq = t >> 6;
        float acc[CI_];
        #pragma unroll
        for (int o = 0; o < CI_; ++o) acc[o] = 0.f;
        float dd = 0.f;
        #pragma unroll 4
        for (int cl = 0; cl < 16; ++cl) {
            int c = cq * 16 + cl;
            float xv = tile[c][nl];
            dd += xv * xv;
            #pragma unroll
            for (int o = 0; o < CI_; ++o) acc[o] += Wg[o * C_ + c] * xv;
        }
        #pragma unroll
        for (int o = 0; o < CI_; ++o) part[cq][nl][o] = acc[o];
        part[cq][nl][32] = dd;
    }
    __syncthreads();
    // (c) reduce + write gx
    {
        const int o = t >> 3, nr = (t & 7) * 8;
        u16x8 w;
        #pragma unroll
        for (int j = 0; j < 8; ++j) {
            int n = nr + j;
            float s = part[0][n][o] + part[1][n][o] + part[2][n][o] + part[3][n][o]
                    + bg[o];
            w[j] = f2bf(s);
        }
        *(u16x8*)(gx + (size_t)(b * CI_ + o) * N_ + n0 + nr) = w;
    }
    // (d) write scaled diag
    if (t < 64)
        diagS[(size_t)b * N_ + n0 + t] = L2E *
            (part[0][t][32] + part[1][t][32] + part[2][t][32] + part[3][t][32]);
}

// ---------------------------------------------------------------------------
// Kernel 2: flash partial. Grid 1024 = b(4) x qtile(64) x kq(4). Block 256 =
// 4 waves; each wave: all 64 queries x a private 256-key subset (8x32-key
// tiles). Direct global fragment loads (L2-hot). LDS only for the in-wave
// P C->A layout round trip and the final 4-wave additive merge.
// MFMA 16x16x32 bf16 layouts (verified):
//   A: [m=lane&15][k=quad*8+j]  B: [k=quad*8+j][n=lane&15]  D: row=quad*4+r, col=lane&15
// ---------------------------------------------------------------------------
__device__ __forceinline__ f32x4 mfma16(bf16x8 a, bf16x8 b, f32x4 c) {
    return __builtin_amdgcn_mfma_f32_16x16x32_bf16(a, b, c, 0, 0, 0);
}

__global__ __launch_bounds__(256, 4) void k_flash(
    const unsigned short* __restrict__ xT, const unsigned short* __restrict__ xq,
    const unsigned short* __restrict__ gx, const float* __restrict__ diagS,
    float* __restrict__ ypart, float* __restrict__ lpart)
{
    __shared__ __align__(16) char smem[34816];
    unsigned short* Pl = (unsigned short*)smem;   // loop: [4 wave][64 q][40 key]
    float*          ym = (float*)smem;            // epilogue: [4 wave][64 q][34]

    const int tid  = threadIdx.x;
    const int wave = tid >> 6, lane = tid & 63;
    const int quad = lane >> 4, li = lane & 15;
    const int bi  = blockIdx.x;
    const int kq  = bi & 3;
    const int qtb = (bi >> 2) & 63;
    const int b   = bi >> 8;
    const int q0  = qtb * 64;

    const unsigned short* xTb = xT + (size_t)b * N_ * C_;
    const unsigned short* xqb = xq + (size_t)b * N_ * C_;
    const unsigned short* gxb = gx + (size_t)(b * CI_) * N_;

    // negated scaled shift per 16-q group (query = column li of S^T)
    float nKq[4];
    #pragma unroll
    for (int qt = 0; qt < 4; ++qt)
        nKq[qt] = -diagS[(size_t)b * N_ + q0 + qt * 16 + li];

    // Q fragments (B-operand, pre-scaled by log2e), register-resident
    bf16x8 Qf[4][2];
    #pragma unroll
    for (int qt = 0; qt < 4; ++qt)
        #pragma unroll
        for (int kc = 0; kc < 2; ++kc)
            Qf[qt][kc] = *(const bf16x8*)(xqb + (size_t)(q0 + qt * 16 + li) * C_
                                          + kc * 32 + quad * 8);

    f32x4 Yf[4][2];
    #pragma unroll
    for (int qt = 0; qt < 4; ++qt)
        #pragma unroll
        for (int ot = 0; ot < 2; ++ot)
            Yf[qt][ot] = (f32x4){0.f, 0.f, 0.f, 0.f};
    float lacc[4] = {0.f, 0.f, 0.f, 0.f};

    const int keybase = kq * 1024 + wave * 256;   // wave-private keys

    for (int tl = 0; tl < 8; ++tl) {
        const int k0 = keybase + tl * 32;

        bf16x8 A[2][2];
        #pragma unroll
        for (int kt = 0; kt < 2; ++kt)
            #pragma unroll
            for (int kc = 0; kc < 2; ++kc)
                A[kt][kc] = *(const bf16x8*)(xTb + (size_t)(k0 + kt * 16 + li) * C_
                                             + kc * 32 + quad * 8);
        bf16x8 Bv[2];
        #pragma unroll
        for (int ot = 0; ot < 2; ++ot)
            Bv[ot] = *(const bf16x8*)(gxb + (size_t)(ot * 16 + li) * N_
                                      + k0 + quad * 8);

        // ---- S = log2e*(K·Q) - K'[q], shift carried in accumulator init ----
        f32x4 S[2][4];
        #pragma unroll
        for (int kt = 0; kt < 2; ++kt)
            #pragma unroll
            for (int qt = 0; qt < 4; ++qt) {
                f32x4 z = (f32x4){nKq[qt], nKq[qt], nKq[qt], nKq[qt]};
                z = mfma16(A[kt][0], Qf[qt][0], z);
                S[kt][qt] = mfma16(A[kt][1], Qf[qt][1], z);
            }

        // ---- p = exp2(S); accumulate l; pack P (perm-truncate) -> LDS ----
        #pragma unroll
        for (int qt = 0; qt < 4; ++qt) {
            float p[2][4];
            #pragma unroll
            for (int kt = 0; kt < 2; ++kt)
                #pragma unroll
                for (int r = 0; r < 4; ++r) {
                    p[kt][r] = __builtin_amdgcn_exp2f(S[kt][qt][r]);
                    lacc[qt] += p[kt][r];
                }
            #pragma unroll
            for (int kt = 0; kt < 2; ++kt) {
                uint2 wv;
                wv.x = __builtin_amdgcn_perm(__float_as_uint(p[kt][1]),
                                             __float_as_uint(p[kt][0]), 0x07060302);
                wv.y = __builtin_amdgcn_perm(__float_as_uint(p[kt][3]),
                                             __float_as_uint(p[kt][2]), 0x07060302);
                *(uint2*)(Pl + (wave * 64 + qt * 16 + li) * 40 + kt * 16 + quad * 4) = wv;
            }
        }

        // ---- Y += P (64q x 32key) * V (32key x 32o) ----
        #pragma unroll
        for (int qt = 0; qt < 4; ++qt) {
            bf16x8 Ap = *(const bf16x8*)(Pl + (wave * 64 + qt * 16 + li) * 40 + quad * 8);
            #pragma unroll
            for (int ot = 0; ot < 2; ++ot)
                Yf[qt][ot] = mfma16(Ap, Bv[ot], Yf[qt][ot]);
        }
    }

    // finalize l: sum across quads -> every lane holds total for its query li
    #pragma unroll
    for (int qt = 0; qt < 4; ++qt) {
        lacc[qt] += __shfl_xor(lacc[qt], 16, 64);
        lacc[qt] += __shfl_xor(lacc[qt], 32, 64);
    }

    __syncthreads();   // Pl dead; switch LDS to merge layout
    #pragma unroll
    for (int qt = 0; qt < 4; ++qt) {
        #pragma unroll
        for (int ot = 0; ot < 2; ++ot)
            #pragma unroll
            for (int r = 0; r < 4; ++r)
                ym[(wave * 64 + qt * 16 + quad * 4 + r) * 34 + ot * 16 + li] = Yf[qt][ot][r];
        if (quad == 0)
            ym[(wave * 64 + qt * 16 + li) * 34 + 32] = lacc[qt];
    }
    __syncthreads();
    {
        const int q = tid >> 2, og = tid & 3;
        const size_t pbase = (size_t)(b * 64 + qtb) * 4 + kq;
        float* yp = ypart + pbase * 2048 + q * 32;
        #pragma unroll
        for (int j = 0; j < 8; ++j) {
            int o = og * 8 + j;
            yp[o] = ym[(0 * 64 + q) * 34 + o] + ym[(1 * 64 + q) * 34 + o]
                  + ym[(2 * 64 + q) * 34 + o] + ym[(3 * 64 + q) * 34 + o];
        }
        if (og == 0)
            lpart[pbase * 64 + q] = ym[(0 * 64 + q) * 34 + 32] + ym[(1 * 64 + q) * 34 + 32]
                                  + ym[(2 * 64 + q) * 34 + 32] + ym[(3 * 64 + q) * 34 + 32];
    }
}

// ---------------------------------------------------------------------------
// Kernel 3: merge 4 key-quarter partials (plain add) + Wz epilogue + residual.
// Grid: 256 blocks = b x qtile. Block 256 threads.
// ---------------------------------------------------------------------------
__global__ __launch_bounds__(256) void k_merge(
    const float* __restrict__ ypart, const float* __restrict__ lpart,
    const float* __restrict__ x, const float* __restrict__ Wz,
    const float* __restrict__ bz, float* __restrict__ out)
{
    __shared__ float yfin[64][33];
    const int t   = threadIdx.x;
    const int b   = blockIdx.x >> 6;
    const int qtb = blockIdx.x & 63;
    const int q0  = qtb * 64;

    {
        const int q = t >> 2, og = t & 3;
        const size_t pb = (size_t)(b * 64 + qtb) * 4;
        float l = lpart[(pb + 0) * 64 + q] + lpart[(pb + 1) * 64 + q]
                + lpart[(pb + 2) * 64 + q] + lpart[(pb + 3) * 64 + q];
        float inv = 1.f / l;
        #pragma unroll
        for (int j = 0; j < 8; ++j) {
            int o = og * 8 + j;
            float acc = 0.f;
            #pragma unroll
            for (int kq = 0; kq < 4; ++kq)
                acc += ypart[(pb + kq) * 2048 + q * 32 + o];
            yfin[q][o] = acc * inv;
        }
    }
    __syncthreads();
    {
        const int q = t & 63, c0 = t >> 6;
        #pragma unroll
        for (int i = 0; i < 16; ++i) {
            int cout = c0 + i * 4;
            float acc = bz[cout];
            #pragma unroll
            for (int o = 0; o < CI_; ++o)
                acc += Wz[cout * CI_ + o] * yfin[q][o];
            size_t oidx = (size_t)(b * C_ + cout) * N_ + q0 + q;
            out[oidx] = acc + x[oidx];
        }
    }
}

// ---------------------------------------------------------------------------
extern "C" void kernel_launch(void* const* d_in, const int* in_sizes, int n_in,
                              void* d_out, int out_size, void* d_ws, size_t ws_size,
                              hipStream_t stream) {
    (void)in_sizes; (void)n_in; (void)out_size; (void)ws_size;
    const float* x  = (const float*)d_in[0];
    const float* Wg = (const float*)d_in[1];
    const float* bg = (const float*)d_in[2];
    const float* Wz = (const float*)d_in[3];
    const float* bz = (const float*)d_in[4];
    float* out = (float*)d_out;

    // ws: xT 2MB | xq 2MB | gx 1MB | diagS 64KB | ypart 8MB | lpart 256KB
    unsigned short* xT = (unsigned short*)d_ws;
    unsigned short* xq = (unsigned short*)((char*)d_ws + 2097152);
    unsigned short* gx = (unsigned short*)((char*)d_ws + 4194304);
    float* diagS = (float*)((char*)d_ws + 5242880);
    float* ypart = (float*)((char*)d_ws + 5308416);
    float* lpart = (float*)((char*)d_ws + 13697024);

    hipLaunchKernelGGL(k_prep,  dim3(B_ * (N_ / 64)), dim3(256), 0, stream,
                       x, Wg, bg, xT, xq, gx, diagS);
    hipLaunchKernelGGL(k_flash, dim3(B_ * 64 * 4),    dim3(256), 0, stream,
                       xT, xq, gx, diagS, ypart, lpart);
    hipLaunchKernelGGL(k_merge, dim3(B_ * 64),        dim3(256), 0, stream,
                       ypart, lpart, x, Wz, bz, out);
}

// Round 7
// 123.976 us; speedup vs baseline: 1.4188x; 1.4188x over previous
//
#include <hip/hip_runtime.h>
#include <hip/hip_bf16.h>
#include <math.h>

// NonLocalBlock: B=4, C=64, H=W=64 -> N=4096, CI=32. f32 I/O, bf16 MFMA.
// Softmax: logits s[q][k] = x_q·x_k shifted by diag K[q]=|x_q|^2 (Cauchy-Schwarz
// bounds shifted logits <= ~35, diag-shift = 0 => no overflow, denom >= ~1):
// softmax = pure exp + linear accumulation; key-split partials combine by add.
// Round 7: exp2 path (Q scaled by log2e IN-REGISTER once per block; shift rides
// in MFMA accumulator init; P packed via v_perm truncation). launch_bounds
// (256,3) -- r6's (256,4) capped VGPR=64 and spilled to scratch (256MB WRITE).
#define B_  4
#define C_  64
#define N_  4096
#define CI_ 32
#define L2E 1.4426950408889634f

typedef __attribute__((ext_vector_type(8))) unsigned short u16x8;
typedef __attribute__((ext_vector_type(8))) __bf16        bf16x8;
typedef __attribute__((ext_vector_type(4))) float         f32x4;

union bfu { u16x8 u; bf16x8 b; };

__device__ __forceinline__ unsigned short f2bf(float f) {
    union { float f; unsigned int i; } v; v.f = f;
    unsigned int r = v.i + 0x7FFFu + ((v.i >> 16) & 1u);
    return (unsigned short)(r >> 16);
}

// ---------------------------------------------------------------------------
// Kernel 1 (fused prep): per 64-n tile of one batch:
//   xT[b][n][c] (bf16) <- x transposed (K and Q operand)
//   gx[b][o][n] (bf16) <- Wg x + bg    (V operand)
//   diagS[b][n] (f32)  <- |x_n|^2 * log2e  (softmax shift, base-2)
// Grid 256 = b(4) x ntile(64). Block 256.
// ---------------------------------------------------------------------------
__global__ __launch_bounds__(256) void k_prep(
    const float* __restrict__ x, const float* __restrict__ Wg,
    const float* __restrict__ bg, unsigned short* __restrict__ xT,
    unsigned short* __restrict__ gx, float* __restrict__ diagS)
{
    __shared__ __align__(16) float tile[64][68];
    __shared__ float part[4][64][33];   // o 0..31 = gx, col 32 = diag
    const int t  = threadIdx.x;
    const int b  = blockIdx.x >> 6;
    const int n0 = (blockIdx.x & 63) * 64;

    #pragma unroll
    for (int pass = 0; pass < 4; ++pass) {
        int c   = (t >> 4) + pass * 16;
        int nl4 = (t & 15) * 4;
        float4 v = *(const float4*)(x + (size_t)(b * C_ + c) * N_ + n0 + nl4);
        *(float4*)&tile[c][nl4] = v;
    }
    __syncthreads();

    // (a) xT (bf16 transpose)
    {
        const int n  = t >> 2;
        const int cc = (t & 3) * 16;
        u16x8 a, b2;
        #pragma unroll
        for (int j = 0; j < 8; ++j) {
            a[j]  = f2bf(tile[cc + j][n]);
            b2[j] = f2bf(tile[cc + 8 + j][n]);
        }
        size_t off = (size_t)(b * N_ + n0 + n) * C_ + cc;
        *(u16x8*)(xT + off)     = a;
        *(u16x8*)(xT + off + 8) = b2;
    }
    // (b) gx partial + diag partial
    {
        const int nl = t & 63, cq = t >> 6;
        float acc[CI_];
        #pragma unroll
        for (int o = 0; o < CI_; ++o) acc[o] = 0.f;
        float dd = 0.f;
        #pragma unroll 4
        for (int cl = 0; cl < 16; ++cl) {
            int c = cq * 16 + cl;
            float xv = tile[c][nl];
            dd += xv * xv;
            #pragma unroll
            for (int o = 0; o < CI_; ++o) acc[o] += Wg[o * C_ + c] * xv;
        }
        #pragma unroll
        for (int o = 0; o < CI_; ++o) part[cq][nl][o] = acc[o];
        part[cq][nl][32] = dd;
    }
    __syncthreads();
    // (c) reduce + write gx
    {
        const int o = t >> 3, nr = (t & 7) * 8;
        u16x8 w;
        #pragma unroll
        for (int j = 0; j < 8; ++j) {
            int n = nr + j;
            float s = part[0][n][o] + part[1][n][o] + part[2][n][o] + part[3][n][o]
                    + bg[o];
            w[j] = f2bf(s);
        }
        *(u16x8*)(gx + (size_t)(b * CI_ + o) * N_ + n0 + nr) = w;
    }
    // (d) write scaled diag
    if (t < 64)
        diagS[(size_t)b * N_ + n0 + t] = L2E *
            (part[0][t][32] + part[1][t][32] + part[2][t][32] + part[3][t][32]);
}

// ---------------------------------------------------------------------------
// Kernel 2: flash partial. Grid 1024 = b(4) x qtile(64) x kq(4). Block 256 =
// 4 waves; each wave: all 64 queries x a private 256-key subset (8x32-key
// tiles). Direct global fragment loads (L2-hot xT+gx = 3MB). LDS only for the
// in-wave P C->A layout round trip and the final 4-wave additive merge.
// MFMA 16x16x32 bf16 layouts (verified):
//   A: [m=lane&15][k=quad*8+j]  B: [k=quad*8+j][n=lane&15]  D: row=quad*4+r, col=lane&15
// ---------------------------------------------------------------------------
__device__ __forceinline__ f32x4 mfma16(bf16x8 a, bf16x8 b, f32x4 c) {
    return __builtin_amdgcn_mfma_f32_16x16x32_bf16(a, b, c, 0, 0, 0);
}

__global__ __launch_bounds__(256, 3) void k_flash(
    const unsigned short* __restrict__ xT, const unsigned short* __restrict__ gx,
    const float* __restrict__ diagS,
    float* __restrict__ ypart, float* __restrict__ lpart)
{
    __shared__ __align__(16) char smem[34816];
    unsigned short* Pl = (unsigned short*)smem;   // loop: [4 wave][64 q][40 key]
    float*          ym = (float*)smem;            // epilogue: [4 wave][64 q][34]

    const int tid  = threadIdx.x;
    const int wave = tid >> 6, lane = tid & 63;
    const int quad = lane >> 4, li = lane & 15;
    const int bi  = blockIdx.x;
    const int kq  = bi & 3;
    const int qtb = (bi >> 2) & 63;
    const int b   = bi >> 8;
    const int q0  = qtb * 64;

    const unsigned short* xTb = xT + (size_t)b * N_ * C_;
    const unsigned short* gxb = gx + (size_t)(b * CI_) * N_;

    // negated scaled shift per 16-q group (query = column li of S^T)
    float nKq[4];
    #pragma unroll
    for (int qt = 0; qt < 4; ++qt)
        nKq[qt] = -diagS[(size_t)b * N_ + q0 + qt * 16 + li];

    // Q fragments (B-operand): load from xT, scale by log2e in-register (RTN),
    // once per block. Q = column li of S^T per 16-q group qt.
    bf16x8 Qf[4][2];
    #pragma unroll
    for (int qt = 0; qt < 4; ++qt)
        #pragma unroll
        for (int kc = 0; kc < 2; ++kc) {
            uint4 qr = *(const uint4*)(xTb + (size_t)(q0 + qt * 16 + li) * C_
                                       + kc * 32 + quad * 8);
            unsigned wv[4] = {qr.x, qr.y, qr.z, qr.w};
            bfu cv;
            #pragma unroll
            for (int j = 0; j < 4; ++j) {
                float lo = __uint_as_float(wv[j] << 16) * L2E;
                float hi = __uint_as_float(wv[j] & 0xFFFF0000u) * L2E;
                cv.u[2 * j]     = f2bf(lo);
                cv.u[2 * j + 1] = f2bf(hi);
            }
            Qf[qt][kc] = cv.b;
        }

    f32x4 Yf[4][2];
    #pragma unroll
    for (int qt = 0; qt < 4; ++qt)
        #pragma unroll
        for (int ot = 0; ot < 2; ++ot)
            Yf[qt][ot] = (f32x4){0.f, 0.f, 0.f, 0.f};
    float lacc[4] = {0.f, 0.f, 0.f, 0.f};

    const int keybase = kq * 1024 + wave * 256;   // wave-private keys

    for (int tl = 0; tl < 8; ++tl) {
        const int k0 = keybase + tl * 32;

        bf16x8 A[2][2];
        #pragma unroll
        for (int kt = 0; kt < 2; ++kt)
            #pragma unroll
            for (int kc = 0; kc < 2; ++kc)
                A[kt][kc] = *(const bf16x8*)(xTb + (size_t)(k0 + kt * 16 + li) * C_
                                             + kc * 32 + quad * 8);
        bf16x8 Bv[2];
        #pragma unroll
        for (int ot = 0; ot < 2; ++ot)
            Bv[ot] = *(const bf16x8*)(gxb + (size_t)(ot * 16 + li) * N_
                                      + k0 + quad * 8);

        // per-16-key half: S -> exp2 -> pack -> LDS   (halves S register liveness)
        #pragma unroll
        for (int kt = 0; kt < 2; ++kt) {
            f32x4 S[4];
            #pragma unroll
            for (int qt = 0; qt < 4; ++qt) {
                f32x4 z = (f32x4){nKq[qt], nKq[qt], nKq[qt], nKq[qt]};
                z = mfma16(A[kt][0], Qf[qt][0], z);
                S[qt] = mfma16(A[kt][1], Qf[qt][1], z);
            }
            #pragma unroll
            for (int qt = 0; qt < 4; ++qt) {
                float p[4];
                #pragma unroll
                for (int r = 0; r < 4; ++r) {
                    p[r] = __builtin_amdgcn_exp2f(S[qt][r]);
                    lacc[qt] += p[r];
                }
                uint2 wv;
                wv.x = __builtin_amdgcn_perm(__float_as_uint(p[1]),
                                             __float_as_uint(p[0]), 0x07060302);
                wv.y = __builtin_amdgcn_perm(__float_as_uint(p[3]),
                                             __float_as_uint(p[2]), 0x07060302);
                *(uint2*)(Pl + (wave * 64 + qt * 16 + li) * 40 + kt * 16 + quad * 4) = wv;
            }
        }

        // ---- Y += P (64q x 32key) * V (32key x 32o) ----
        #pragma unroll
        for (int qt = 0; qt < 4; ++qt) {
            bf16x8 Ap = *(const bf16x8*)(Pl + (wave * 64 + qt * 16 + li) * 40 + quad * 8);
            #pragma unroll
            for (int ot = 0; ot < 2; ++ot)
                Yf[qt][ot] = mfma16(Ap, Bv[ot], Yf[qt][ot]);
        }
    }

    // finalize l: sum across quads -> every lane holds total for its query li
    #pragma unroll
    for (int qt = 0; qt < 4; ++qt) {
        lacc[qt] += __shfl_xor(lacc[qt], 16, 64);
        lacc[qt] += __shfl_xor(lacc[qt], 32, 64);
    }

    __syncthreads();   // Pl dead; switch LDS to merge layout
    #pragma unroll
    for (int qt = 0; qt < 4; ++qt) {
        #pragma unroll
        for (int ot = 0; ot < 2; ++ot)
            #pragma unroll
            for (int r = 0; r < 4; ++r)
                ym[(wave * 64 + qt * 16 + quad * 4 + r) * 34 + ot * 16 + li] = Yf[qt][ot][r];
        if (quad == 0)
            ym[(wave * 64 + qt * 16 + li) * 34 + 32] = lacc[qt];
    }
    __syncthreads();
    {
        const int q = tid >> 2, og = tid & 3;
        const size_t pbase = (size_t)(b * 64 + qtb) * 4 + kq;
        float* yp = ypart + pbase * 2048 + q * 32;
        #pragma unroll
        for (int j = 0; j < 8; ++j) {
            int o = og * 8 + j;
            yp[o] = ym[(0 * 64 + q) * 34 + o] + ym[(1 * 64 + q) * 34 + o]
                  + ym[(2 * 64 + q) * 34 + o] + ym[(3 * 64 + q) * 34 + o];
        }
        if (og == 0)
            lpart[pbase * 64 + q] = ym[(0 * 64 + q) * 34 + 32] + ym[(1 * 64 + q) * 34 + 32]
                                  + ym[(2 * 64 + q) * 34 + 32] + ym[(3 * 64 + q) * 34 + 32];
    }
}

// ---------------------------------------------------------------------------
// Kernel 3: merge 4 key-quarter partials (plain add) + Wz epilogue + residual.
// Grid: 256 blocks = b x qtile. Block 256 threads.
// ---------------------------------------------------------------------------
__global__ __launch_bounds__(256) void k_merge(
    const float* __restrict__ ypart, const float* __restrict__ lpart,
    const float* __restrict__ x, const float* __restrict__ Wz,
    const float* __restrict__ bz, float* __restrict__ out)
{
    __shared__ float yfin[64][33];
    const int t   = threadIdx.x;
    const int b   = blockIdx.x >> 6;
    const int qtb = blockIdx.x & 63;
    const int q0  = qtb * 64;

    {
        const int q = t >> 2, og = t & 3;
        const size_t pb = (size_t)(b * 64 + qtb) * 4;
        float l = lpart[(pb + 0) * 64 + q] + lpart[(pb + 1) * 64 + q]
                + lpart[(pb + 2) * 64 + q] + lpart[(pb + 3) * 64 + q];
        float inv = 1.f / l;
        #pragma unroll
        for (int j = 0; j < 8; ++j) {
            int o = og * 8 + j;
            float acc = 0.f;
            #pragma unroll
            for (int kq = 0; kq < 4; ++kq)
                acc += ypart[(pb + kq) * 2048 + q * 32 + o];
            yfin[q][o] = acc * inv;
        }
    }
    __syncthreads();
    {
        const int q = t & 63, c0 = t >> 6;
        #pragma unroll
        for (int i = 0; i < 16; ++i) {
            int cout = c0 + i * 4;
            float acc = bz[cout];
            #pragma unroll
            for (int o = 0; o < CI_; ++o)
                acc += Wz[cout * CI_ + o] * yfin[q][o];
            size_t oidx = (size_t)(b * C_ + cout) * N_ + q0 + q;
            out[oidx] = acc + x[oidx];
        }
    }
}

// ---------------------------------------------------------------------------
extern "C" void kernel_launch(void* const* d_in, const int* in_sizes, int n_in,
                              void* d_out, int out_size, void* d_ws, size_t ws_size,
                              hipStream_t stream) {
    (void)in_sizes; (void)n_in; (void)out_size; (void)ws_size;
    const float* x  = (const float*)d_in[0];
    const float* Wg = (const float*)d_in[1];
    const float* bg = (const float*)d_in[2];
    const float* Wz = (const float*)d_in[3];
    const float* bz = (const float*)d_in[4];
    float* out = (float*)d_out;

    // ws: xT 2MB | gx 1MB | diagS 64KB | ypart 8MB | lpart 256KB (~11.3MB)
    unsigned short* xT = (unsigned short*)d_ws;
    unsigned short* gx = (unsigned short*)((char*)d_ws + 2097152);
    float* diagS = (float*)((char*)d_ws + 3145728);
    float* ypart = (float*)((char*)d_ws + 3211264);
    float* lpart = (float*)((char*)d_ws + 11599872);

    hipLaunchKernelGGL(k_prep,  dim3(B_ * (N_ / 64)), dim3(256), 0, stream,
                       x, Wg, bg, xT, gx, diagS);
    hipLaunchKernelGGL(k_flash, dim3(B_ * 64 * 4),    dim3(256), 0, stream,
                       xT, gx, diagS, ypart, lpart);
    hipLaunchKernelGGL(k_merge, dim3(B_ * 64),        dim3(256), 0, stream,
                       ypart, lpart, x, Wz, bz, out);
}

// Round 8
// 118.064 us; speedup vs baseline: 1.4898x; 1.0501x over previous
//
#include <hip/hip_runtime.h>
#include <hip/hip_bf16.h>
#include <math.h>

// NonLocalBlock: B=4, C=64, H=W=64 -> N=4096, CI=32. f32 I/O, bf16 MFMA.
// Shift-softmax: logits s[q][k] = x_q·x_k shifted by diag K[q]=|x_q|^2
// (Cauchy-Schwarz: shifted logits <= ~35, diag term = 0 => no overflow,
// denom >= ~1): softmax = pure exp2 + linear accumulation, key-split
// partials combine by plain addition. Q scaled by log2e in-register.
// Round 8: k_prep/k_merge re-gridded to 1024 blocks (r7 ran 1 block/CU);
// k_flash gets a 2-deep register prefetch pipeline (global loads of tile
// t+1 issue before compute of tile t).
#define B_  4
#define C_  64
#define N_  4096
#define CI_ 32
#define L2E 1.4426950408889634f

typedef __attribute__((ext_vector_type(8))) unsigned short u16x8;
typedef __attribute__((ext_vector_type(4))) unsigned short u16x4;
typedef __attribute__((ext_vector_type(8))) __bf16        bf16x8;
typedef __attribute__((ext_vector_type(4))) float         f32x4;

union bfu { u16x8 u; bf16x8 b; };

__device__ __forceinline__ unsigned short f2bf(float f) {
    union { float f; unsigned int i; } v; v.f = f;
    unsigned int r = v.i + 0x7FFFu + ((v.i >> 16) & 1u);
    return (unsigned short)(r >> 16);
}

// ---------------------------------------------------------------------------
// Kernel 1 (fused prep): per 16-n tile: xT[b][n][c] (bf16 transpose),
// gx[b][o][n] (bf16, Wg x + bg), diagS[b][n] (f32, |x_n|^2 * log2e).
// Grid 1024 = b(4) x ntile(256). Block 256 (4 blocks/CU-class parallelism).
// ---------------------------------------------------------------------------
__global__ __launch_bounds__(256) void k_prep(
    const float* __restrict__ x, const float* __restrict__ Wg,
    const float* __restrict__ bg, unsigned short* __restrict__ xT,
    unsigned short* __restrict__ gx, float* __restrict__ diagS)
{
    __shared__ __align__(16) float tile[64][20];          // 64 c x 16 n
    __shared__ unsigned short gout[CI_][16];
    const int t  = threadIdx.x;
    const int b  = blockIdx.x >> 8;
    const int n0 = (blockIdx.x & 255) * 16;

    {   // load x[64 c][16 n] (float4 per thread)
        const int c  = t >> 2;
        const int nq = (t & 3) * 4;
        float4 v = *(const float4*)(x + (size_t)(b * C_ + c) * N_ + n0 + nq);
        *(float4*)&tile[c][nq] = v;
    }
    __syncthreads();

    // (a) transpose -> xT  (lane=cg fastest => coalesced 8B writes)
    {
        const int cg = t & 15, n = t >> 4;
        u16x4 w;
        #pragma unroll
        for (int j = 0; j < 4; ++j) w[j] = f2bf(tile[cg * 4 + j][n]);
        *(u16x4*)(xT + (size_t)(b * N_ + n0 + n) * C_ + cg * 4) = w;
    }
    // (b) gx (2 o's per thread) + diag
    {
        const int n = t >> 4, oh = t & 15;
        const int o0 = oh * 2, o1 = o0 + 1;
        float a0 = 0.f, a1 = 0.f, dd = 0.f;
        #pragma unroll
        for (int c4 = 0; c4 < 16; ++c4) {
            float4 w0 = *(const float4*)(Wg + o0 * C_ + c4 * 4);
            float4 w1 = *(const float4*)(Wg + o1 * C_ + c4 * 4);
            float x0 = tile[c4 * 4 + 0][n], x1 = tile[c4 * 4 + 1][n];
            float x2 = tile[c4 * 4 + 2][n], x3 = tile[c4 * 4 + 3][n];
            a0 += w0.x * x0 + w0.y * x1 + w0.z * x2 + w0.w * x3;
            a1 += w1.x * x0 + w1.y * x1 + w1.z * x2 + w1.w * x3;
            dd += x0 * x0 + x1 * x1 + x2 * x2 + x3 * x3;
        }
        gout[o0][n] = f2bf(a0 + bg[o0]);
        gout[o1][n] = f2bf(a1 + bg[o1]);
        if (oh == 0) diagS[(size_t)b * N_ + n0 + n] = L2E * dd;
    }
    __syncthreads();
    // (c) write gx rows (o-major)
    if (t < 128) {
        const int o = t >> 2, n4 = (t & 3) * 4;
        u16x4 w;
        #pragma unroll
        for (int j = 0; j < 4; ++j) w[j] = gout[o][n4 + j];
        *(u16x4*)(gx + (size_t)(b * CI_ + o) * N_ + n0 + n4) = w;
    }
}

// ---------------------------------------------------------------------------
// Kernel 2: flash partial. Grid 1024 = b(4) x qtile(64) x kq(4). Block 256 =
// 4 waves; each wave: all 64 queries x a private 256-key subset (8x32-key
// tiles), 2-deep register prefetch on the A/Bv global loads (L2-hot 3MB).
// LDS only for the in-wave P C->A layout round trip + final additive merge.
// MFMA 16x16x32 bf16 layouts (verified):
//   A: [m=lane&15][k=quad*8+j]  B: [k=quad*8+j][n=lane&15]  D: row=quad*4+r, col=lane&15
// ---------------------------------------------------------------------------
__device__ __forceinline__ f32x4 mfma16(bf16x8 a, bf16x8 b, f32x4 c) {
    return __builtin_amdgcn_mfma_f32_16x16x32_bf16(a, b, c, 0, 0, 0);
}

__global__ __launch_bounds__(256, 3) void k_flash(
    const unsigned short* __restrict__ xT, const unsigned short* __restrict__ gx,
    const float* __restrict__ diagS,
    float* __restrict__ ypart, float* __restrict__ lpart)
{
    __shared__ __align__(16) char smem[34816];
    unsigned short* Pl = (unsigned short*)smem;   // loop: [4 wave][64 q][40 key]
    float*          ym = (float*)smem;            // epilogue: [4 wave][64 q][34]

    const int tid  = threadIdx.x;
    const int wave = tid >> 6, lane = tid & 63;
    const int quad = lane >> 4, li = lane & 15;
    const int bi  = blockIdx.x;
    const int kq  = bi & 3;
    const int qtb = (bi >> 2) & 63;
    const int b   = bi >> 8;
    const int q0  = qtb * 64;

    const unsigned short* xTb = xT + (size_t)b * N_ * C_;
    const unsigned short* gxb = gx + (size_t)(b * CI_) * N_;

    float nKq[4];
    #pragma unroll
    for (int qt = 0; qt < 4; ++qt)
        nKq[qt] = -diagS[(size_t)b * N_ + q0 + qt * 16 + li];

    // Q fragments (B-operand): scale by log2e in-register once per block
    bf16x8 Qf[4][2];
    #pragma unroll
    for (int qt = 0; qt < 4; ++qt)
        #pragma unroll
        for (int kc = 0; kc < 2; ++kc) {
            uint4 qr = *(const uint4*)(xTb + (size_t)(q0 + qt * 16 + li) * C_
                                       + kc * 32 + quad * 8);
            unsigned wv[4] = {qr.x, qr.y, qr.z, qr.w};
            bfu cv;
            #pragma unroll
            for (int j = 0; j < 4; ++j) {
                float lo = __uint_as_float(wv[j] << 16) * L2E;
                float hi = __uint_as_float(wv[j] & 0xFFFF0000u) * L2E;
                cv.u[2 * j]     = f2bf(lo);
                cv.u[2 * j + 1] = f2bf(hi);
            }
            Qf[qt][kc] = cv.b;
        }

    f32x4 Yf[4][2];
    #pragma unroll
    for (int qt = 0; qt < 4; ++qt)
        #pragma unroll
        for (int ot = 0; ot < 2; ++ot)
            Yf[qt][ot] = (f32x4){0.f, 0.f, 0.f, 0.f};
    float lacc[4] = {0.f, 0.f, 0.f, 0.f};

    const int keybase = kq * 1024 + wave * 256;   // wave-private keys

    auto load_tile = [&](int k0, bf16x8 Ad[2][2], bf16x8 Bd[2]) {
        #pragma unroll
        for (int kt = 0; kt < 2; ++kt)
            #pragma unroll
            for (int kc = 0; kc < 2; ++kc)
                Ad[kt][kc] = *(const bf16x8*)(xTb + (size_t)(k0 + kt * 16 + li) * C_
                                              + kc * 32 + quad * 8);
        #pragma unroll
        for (int ot = 0; ot < 2; ++ot)
            Bd[ot] = *(const bf16x8*)(gxb + (size_t)(ot * 16 + li) * N_
                                      + k0 + quad * 8);
    };

    bf16x8 Ab[2][2][2], Bb[2][2];
    load_tile(keybase, Ab[0], Bb[0]);

    #pragma unroll
    for (int tl = 0; tl < 8; ++tl) {
        const int cur = tl & 1, nxt = cur ^ 1;
        if (tl < 7) load_tile(keybase + (tl + 1) * 32, Ab[nxt], Bb[nxt]);

        // per-16-key half: S -> exp2 -> pack -> LDS
        #pragma unroll
        for (int kt = 0; kt < 2; ++kt) {
            f32x4 S[4];
            #pragma unroll
            for (int qt = 0; qt < 4; ++qt) {
                f32x4 z = (f32x4){nKq[qt], nKq[qt], nKq[qt], nKq[qt]};
                z = mfma16(Ab[cur][kt][0], Qf[qt][0], z);
                S[qt] = mfma16(Ab[cur][kt][1], Qf[qt][1], z);
            }
            #pragma unroll
            for (int qt = 0; qt < 4; ++qt) {
                float p[4];
                #pragma unroll
                for (int r = 0; r < 4; ++r) {
                    p[r] = __builtin_amdgcn_exp2f(S[qt][r]);
                    lacc[qt] += p[r];
                }
                uint2 wv;
                wv.x = __builtin_amdgcn_perm(__float_as_uint(p[1]),
                                             __float_as_uint(p[0]), 0x07060302);
                wv.y = __builtin_amdgcn_perm(__float_as_uint(p[3]),
                                             __float_as_uint(p[2]), 0x07060302);
                *(uint2*)(Pl + (wave * 64 + qt * 16 + li) * 40 + kt * 16 + quad * 4) = wv;
            }
        }

        // Y += P (64q x 32key) * V (32key x 32o)
        #pragma unroll
        for (int qt = 0; qt < 4; ++qt) {
            bf16x8 Ap = *(const bf16x8*)(Pl + (wave * 64 + qt * 16 + li) * 40 + quad * 8);
            #pragma unroll
            for (int ot = 0; ot < 2; ++ot)
                Yf[qt][ot] = mfma16(Ap, Bb[cur][ot], Yf[qt][ot]);
        }
    }

    #pragma unroll
    for (int qt = 0; qt < 4; ++qt) {
        lacc[qt] += __shfl_xor(lacc[qt], 16, 64);
        lacc[qt] += __shfl_xor(lacc[qt], 32, 64);
    }

    __syncthreads();   // Pl dead; switch LDS to merge layout
    #pragma unroll
    for (int qt = 0; qt < 4; ++qt) {
        #pragma unroll
        for (int ot = 0; ot < 2; ++ot)
            #pragma unroll
            for (int r = 0; r < 4; ++r)
                ym[(wave * 64 + qt * 16 + quad * 4 + r) * 34 + ot * 16 + li] = Yf[qt][ot][r];
        if (quad == 0)
            ym[(wave * 64 + qt * 16 + li) * 34 + 32] = lacc[qt];
    }
    __syncthreads();
    {
        const int q = tid >> 2, og = tid & 3;
        const size_t pbase = (size_t)(b * 64 + qtb) * 4 + kq;
        float* yp = ypart + pbase * 2048 + q * 32;
        #pragma unroll
        for (int j = 0; j < 8; ++j) {
            int o = og * 8 + j;
            yp[o] = ym[(0 * 64 + q) * 34 + o] + ym[(1 * 64 + q) * 34 + o]
                  + ym[(2 * 64 + q) * 34 + o] + ym[(3 * 64 + q) * 34 + o];
        }
        if (og == 0)
            lpart[pbase * 64 + q] = ym[(0 * 64 + q) * 34 + 32] + ym[(1 * 64 + q) * 34 + 32]
                                  + ym[(2 * 64 + q) * 34 + 32] + ym[(3 * 64 + q) * 34 + 32];
    }
}

// ---------------------------------------------------------------------------
// Kernel 3: merge 4 key-quarter partials + Wz epilogue + residual.
// Grid 1024 = b(4) x qtile(256) of 16 q. Block 256.
// ---------------------------------------------------------------------------
__global__ __launch_bounds__(256) void k_merge(
    const float* __restrict__ ypart, const float* __restrict__ lpart,
    const float* __restrict__ x, const float* __restrict__ Wz,
    const float* __restrict__ bz, float* __restrict__ out)
{
    __shared__ __align__(16) float yfin[16][36];
    const int t   = threadIdx.x;
    const int b   = blockIdx.x >> 8;
    const int qt  = blockIdx.x & 255;
    const int q0  = qt * 16;
    const int qtb64 = qt >> 2, sub = qt & 3;
    const size_t pb = (size_t)(b * 64 + qtb64) * 4;

    if (t < 128) {
        const int q = t >> 3, o4 = (t & 7) * 4;
        const int q64 = sub * 16 + q;
        float l = lpart[(pb + 0) * 64 + q64] + lpart[(pb + 1) * 64 + q64]
                + lpart[(pb + 2) * 64 + q64] + lpart[(pb + 3) * 64 + q64];
        float inv = 1.f / l;
        float4 acc = (float4){0.f, 0.f, 0.f, 0.f};
        #pragma unroll
        for (int kq = 0; kq < 4; ++kq) {
            float4 v = *(const float4*)(ypart + (pb + kq) * 2048 + q64 * 32 + o4);
            acc.x += v.x; acc.y += v.y; acc.z += v.z; acc.w += v.w;
        }
        yfin[q][o4 + 0] = acc.x * inv;
        yfin[q][o4 + 1] = acc.y * inv;
        yfin[q][o4 + 2] = acc.z * inv;
        yfin[q][o4 + 3] = acc.w * inv;
    }
    __syncthreads();
    {
        const int c = t >> 2, qg = t & 3;   // 4 q per thread
        float acc[4];
        float bzv = bz[c];
        #pragma unroll
        for (int j = 0; j < 4; ++j) acc[j] = bzv;
        #pragma unroll
        for (int o4 = 0; o4 < 8; ++o4) {
            float4 wz = *(const float4*)(Wz + c * CI_ + o4 * 4);
            #pragma unroll
            for (int j = 0; j < 4; ++j) {
                const float* yr = &yfin[qg * 4 + j][o4 * 4];
                acc[j] += wz.x * yr[0] + wz.y * yr[1] + wz.z * yr[2] + wz.w * yr[3];
            }
        }
        size_t oidx = (size_t)(b * C_ + c) * N_ + q0 + qg * 4;
        float4 xr = *(const float4*)(x + oidx);
        float4 ov = (float4){acc[0] + xr.x, acc[1] + xr.y, acc[2] + xr.z, acc[3] + xr.w};
        *(float4*)(out + oidx) = ov;
    }
}

// ---------------------------------------------------------------------------
extern "C" void kernel_launch(void* const* d_in, const int* in_sizes, int n_in,
                              void* d_out, int out_size, void* d_ws, size_t ws_size,
                              hipStream_t stream) {
    (void)in_sizes; (void)n_in; (void)out_size; (void)ws_size;
    const float* x  = (const float*)d_in[0];
    const float* Wg = (const float*)d_in[1];
    const float* bg = (const float*)d_in[2];
    const float* Wz = (const float*)d_in[3];
    const float* bz = (const float*)d_in[4];
    float* out = (float*)d_out;

    // ws: xT 2MB | gx 1MB | diagS 64KB | ypart 8MB | lpart 256KB (~11.3MB)
    unsigned short* xT = (unsigned short*)d_ws;
    unsigned short* gx = (unsigned short*)((char*)d_ws + 2097152);
    float* diagS = (float*)((char*)d_ws + 3145728);
    float* ypart = (float*)((char*)d_ws + 3211264);
    float* lpart = (float*)((char*)d_ws + 11599872);

    hipLaunchKernelGGL(k_prep,  dim3(B_ * 256),    dim3(256), 0, stream,
                       x, Wg, bg, xT, gx, diagS);
    hipLaunchKernelGGL(k_flash, dim3(B_ * 64 * 4), dim3(256), 0, stream,
                       xT, gx, diagS, ypart, lpart);
    hipLaunchKernelGGL(k_merge, dim3(B_ * 256),    dim3(256), 0, stream,
                       ypart, lpart, x, Wz, bz, out);
}